// Round 7
// baseline (236.148 us; speedup 1.0000x reference)
//
#include <hip/hip_runtime.h>
#include <stdint.h>
#include <math.h>

#define B_ 256
#define H_ 128
#define S_ 2048

typedef __attribute__((ext_vector_type(8))) short short8;
typedef __attribute__((ext_vector_type(4))) float f32x4;
typedef __attribute__((ext_vector_type(4))) unsigned int u32x4;

typedef const __attribute__((address_space(1))) void gvoid_t;
typedef __attribute__((address_space(3))) void lvoid_t;

#define SCHED0 __builtin_amdgcn_sched_barrier(0)

// ---------- helpers ----------
__device__ __forceinline__ unsigned short f2bf(float f) {
  uint32_t u = __builtin_bit_cast(uint32_t, f);
  u += 0x7fffu + ((u >> 16) & 1u);          // round-to-nearest-even
  return (unsigned short)(u >> 16);
}

// pack 2 f32 -> 2 bf16 (RNE), 1 VALU op
__device__ __forceinline__ uint32_t cvtpk(float lo, float hi) {
  uint32_t r;
  asm("v_cvt_pk_bf16_f32 %0, %1, %2" : "=v"(r) : "v"(lo), "v"(hi));
  return r;
}

__device__ __forceinline__ float bf2f(unsigned short u) {
  return __builtin_bit_cast(float, (uint32_t)u << 16);
}

// tanh(x) = 1 - 2/(1+e^{2x}); correct limits at +-inf. 5 VALU ops.
__device__ __forceinline__ float tanh5(float x) {
  float e = __builtin_amdgcn_exp2f(x * 2.8853900817779268f);
  float r = __builtin_amdgcn_rcpf(1.0f + e);
  return fmaf(-2.0f, r, 1.0f);
}

// ---------- ws layout (bytes) ----------
#define WS_NEED 4718592u
#define WST_OFF 8388608u
#define WS_T_NEED (WST_OFF + (size_t)B_ * (S_/16) * 4 * 64 * 8 * 2)

__global__ __launch_bounds__(256) void prep_wfrags(
    const float* __restrict__ W, const float* __restrict__ W2,
    unsigned short* __restrict__ wsA) {
  int idx = blockIdx.x * 256 + threadIdx.x;   // 24*4*64*8 = 49152 total
  if (idx >= 24 * 4 * 64 * 8) return;
  int j = idx & 7;
  int lane = (idx >> 3) & 63;
  int t = (idx >> 9) & 3;
  int tile = idx >> 11;
  int li = lane & 15;
  int k = t * 32 + (lane >> 4) * 8 + j;
  float val;
  if (tile < 8)        val = W[(tile * 16 + li) * 384 + k];             // W_a
  else if (tile < 16)  val = W2[((tile - 8) * 16 + li) * 256 + k];      // W2_a
  else                 val = W[((tile - 16) * 16 + li) * 384 + 128 + k];// W_b
  wsA[idx] = f2bf(val);
}

__global__ __launch_bounds__(128) void prep_c1(
    const float* __restrict__ W, const float* __restrict__ dec,
    float* __restrict__ c1) {
  int b = blockIdx.x;
  int h = threadIdx.x;
  __shared__ float sdec[H_];
  sdec[h] = dec[b * H_ + h];
  __syncthreads();
  const float* wr = W + h * 384 + 256;
  float acc = 0.f;
  #pragma unroll 4
  for (int k = 0; k < 128; ++k) acc += wr[k] * sdec[k];
  c1[b * H_ + h] = acc;
}

__global__ void detect_mask(const unsigned char* __restrict__ mb, int* __restrict__ flag) {
  __shared__ int sGT1, sNZ;
  if (threadIdx.x == 0) { sGT1 = 0; sNZ = 0; }
  __syncthreads();
  int gt1 = 0, nz = 0;
  for (int i = threadIdx.x; i < 8192; i += 256) {
    unsigned char c = mb[i];
    if (c > 1) gt1 = 1;
    if ((i & 3) && c) nz = 1;
  }
  if (gt1) atomicOr(&sGT1, 1);
  if (nz)  atomicOr(&sNZ, 1);
  __syncthreads();
  if (threadIdx.x == 0) *flag = sGT1 ? 2 : (sNZ ? 1 : 0);
}

struct D4 { f32x4 v[4]; };

// Stage 1, counted-vmcnt 2-deep pipeline (R6 + race fix). grid (8, B): block
// owns 256 s = 8 chunks of 32 s. 4 waves; wave w: m-tiles {2w,2w+1} in regs;
// converts s-tile (w>>1), t-pair (w&1). LDS 49.6 KB -> 3 blocks/CU.
// RACE FIX vs R6: stageS(c+2)/loadD(c+2) (which overwrite sS[c&1]) are issued
// AFTER barrier B2, when all waves' convert reads of sS[c&1] are complete.
// Per-chunk vm ops/wave (uniform): [1 attns][2 wsT][4 stageS][4 loadD] = 11.
// Ledger: top-of-chunk wait = vmcnt(8) c0, (10) c1, (11) c2..6, (3) c7.
__global__ __launch_bounds__(256, 3) void stage1(
    const float* __restrict__ sEmb, const float* __restrict__ dEmb,
    const unsigned short* __restrict__ wsA, const float* __restrict__ c1,
    const float* __restrict__ v, float* __restrict__ attns,
    unsigned short* __restrict__ wsT) {
  const int b = blockIdx.y;
  const int tid = threadIdx.x;
  const int lane = tid & 63, w = tid >> 6, g = lane >> 4, li = lane & 15;
  const int stl = w >> 1, tp = w & 1;
  __shared__ float sS[2][128 * 32];           // [buf][k][32 s] f32, col^=(((k>>3)&3)<<3)
  __shared__ unsigned short frag[2][8][512];  // [stile][t | 4+t][lane*8] bf16
  __shared__ float spart[4][32];
  __shared__ float sc1[H_], sv[H_];

  const size_t sbase = (size_t)b * H_ * S_;
  const size_t dbase = (size_t)b * S_ * H_;
  const int sblk = blockIdx.x * 256;
  const int CHUNKS = 8;

  // W fragments -> registers (once)
  short8 aW[2][4], aB[2][4];
  #pragma unroll
  for (int mm = 0; mm < 2; ++mm)
    #pragma unroll
    for (int t = 0; t < 4; ++t) {
      aW[mm][t] = *(const short8*)(wsA + (size_t)(((2 * w + mm) * 4 + t) * 64 + lane) * 8);
      aB[mm][t] = *(const short8*)(wsA + (size_t)(((16 + 2 * w + mm) * 4 + t) * 64 + lane) * 8);
    }
  // sc1/sv: wave-uniform instruction count (all waves issue)
  {
    int hh = 32 * w + (lane & 31);
    sc1[hh] = c1[b * H_ + hh];
    sv[hh]  = v[hh];
  }

  // stage one 32-s chunk of static into LDS buf (4 gl_lds/wave, src pre-swizzled)
  auto stageS = [&](int soff2, int buf) {
    #pragma unroll
    for (int i = 0; i < 4; ++i) {
      int rr = 32 * w + 8 * i + (lane >> 3);
      int gcol = (4 * (lane & 7)) ^ (i << 3);
      const float* src = sEmb + sbase + (size_t)rr * S_ + soff2 + gcol;
      __builtin_amdgcn_global_load_lds((gvoid_t*)src,
                                       (lvoid_t*)&sS[buf][(32 * w + 8 * i) * 32], 16, 0, 0);
    }
  };
  // dyn rows for this wave's (stl, tp): 4 x 16B contiguous loads
  auto loadD = [&](int soff2) -> D4 {
    D4 r;
    const float* dr = dEmb + dbase + (size_t)(soff2 + 16 * stl + li) * H_ + 64 * tp + 8 * g;
    r.v[0] = *(const f32x4*)(dr);
    r.v[1] = *(const f32x4*)(dr + 4);
    r.v[2] = *(const f32x4*)(dr + 32);
    r.v[3] = *(const f32x4*)(dr + 36);
    return r;
  };

  SCHED0;
  stageS(sblk, 0);
  SCHED0;
  D4 dvA = loadD(sblk);
  SCHED0;
  stageS(sblk + 32, 1);
  SCHED0;
  D4 dvB = loadD(sblk + 32);
  SCHED0;

  const int colr = (16 * stl + li) ^ (g << 3);   // stored col for static reads

  for (int c = 0; c < CHUNKS; ++c) {
    const int soff = sblk + c * 32;

    // ---- top: counted wait + barrier (NOT vmcnt(0)) ----
    if (c == 0)                 { asm volatile("s_waitcnt vmcnt(8)" ::: "memory"); }
    else if (c == 1)            { asm volatile("s_waitcnt vmcnt(10)" ::: "memory"); }
    else if (c == CHUNKS - 1)   { asm volatile("s_waitcnt vmcnt(3)" ::: "memory"); }
    else                        { asm volatile("s_waitcnt vmcnt(11)" ::: "memory"); }
    asm volatile("s_waitcnt lgkmcnt(0)" ::: "memory");
    SCHED0;
    __builtin_amdgcn_s_barrier();
    SCHED0;

    // ---- attns store for chunk c-1 (1 vm op, wave-uniform) ----
    if (c > 0) {
      int idx = 8 * w + (lane & 7);
      float tot = spart[0][idx] + spart[1][idx] + spart[2][idx] + spart[3][idx];
      if (lane < 8) attns[(size_t)b * S_ + soff - 32 + idx] = tot;
    }

    // ---- convert: this wave's (stl, tp) slice -> frag + wsT (2 vm stores) ----
    {
      const float* sSc = sS[c & 1];
      const f32x4* dvv = (c & 1) ? dvB.v : dvA.v;
      #pragma unroll
      for (int tt = 0; tt < 2; ++tt) {
        const int t = 2 * tp + tt;
        const int rb = (32 * t + 8 * g) * 32 + colr;
        uint32_t s0 = cvtpk(sSc[rb], sSc[rb + 32]);
        uint32_t s1 = cvtpk(sSc[rb + 64], sSc[rb + 96]);
        uint32_t s2 = cvtpk(sSc[rb + 128], sSc[rb + 160]);
        uint32_t s3 = cvtpk(sSc[rb + 192], sSc[rb + 224]);
        u32x4 us = {s0, s1, s2, s3};
        short8 bS = __builtin_bit_cast(short8, us);
        f32x4 a0 = dvv[2 * tt], a1 = dvv[2 * tt + 1];
        uint32_t d0 = cvtpk(a0.x, a0.y);
        uint32_t d1 = cvtpk(a0.z, a0.w);
        uint32_t d2 = cvtpk(a1.x, a1.y);
        uint32_t d3 = cvtpk(a1.z, a1.w);
        u32x4 ud = {d0, d1, d2, d3};
        short8 bD = __builtin_bit_cast(short8, ud);
        *(short8*)&frag[stl][t][lane * 8] = bS;
        *(short8*)&frag[stl][4 + t][lane * 8] = bD;
        *(short8*)&wsT[(((size_t)b * (S_ / 16) + (soff >> 4) + stl) * 4 + t) * 512 + lane * 8] = bS;
      }
    }

    // ---- my LDS reads+writes drained, then barrier: ALL waves' sS reads done ----
    asm volatile("s_waitcnt lgkmcnt(0)" ::: "memory");
    SCHED0;
    __builtin_amdgcn_s_barrier();   // B2: frags visible; sS[c&1] fully consumed
    SCHED0;

    // ---- NOW safe to issue set(c+2) into sS[c&1] (8 vm ops) ----
    if (c + 2 < CHUNKS) {
      stageS(soff + 64, c & 1);
      SCHED0;
      if ((c & 1) == 0) dvA = loadD(soff + 64);
      else              dvB = loadD(soff + 64);
    }
    SCHED0;

    // ---- MFMA phase: 2 s-tiles x K=128, both operands ----
    f32x4 acc[2][2];
    #pragma unroll
    for (int st = 0; st < 2; ++st) { acc[st][0] = (f32x4)0.0f; acc[st][1] = (f32x4)0.0f; }
    #pragma unroll
    for (int st = 0; st < 2; ++st)
      #pragma unroll
      for (int t = 0; t < 4; ++t) {
        short8 bS = *(const short8*)&frag[st][t][lane * 8];
        short8 bD = *(const short8*)&frag[st][4 + t][lane * 8];
        acc[st][0] = __builtin_amdgcn_mfma_f32_16x16x32_bf16(aW[0][t], bS, acc[st][0], 0, 0, 0);
        acc[st][1] = __builtin_amdgcn_mfma_f32_16x16x32_bf16(aW[1][t], bS, acc[st][1], 0, 0, 0);
        acc[st][0] = __builtin_amdgcn_mfma_f32_16x16x32_bf16(aB[0][t], bD, acc[st][0], 0, 0, 0);
        acc[st][1] = __builtin_amdgcn_mfma_f32_16x16x32_bf16(aB[1][t], bD, acc[st][1], 0, 0, 0);
      }

    // ---- epilogue: partial v-dot over this wave's 32 h ----
    #pragma unroll
    for (int st = 0; st < 2; ++st) {
      float part = 0.f;
      #pragma unroll
      for (int mm = 0; mm < 2; ++mm)
        #pragma unroll
        for (int r = 0; r < 4; ++r) {
          int h = 32 * w + 16 * mm + 4 * g + r;
          part += sv[h] * tanh5(acc[st][mm][r] + sc1[h]);
        }
      part += __shfl_xor(part, 16);
      part += __shfl_xor(part, 32);
      if (lane < 16) spart[w][16 * st + li] = part;
    }
  }

  asm volatile("s_waitcnt lgkmcnt(0)" ::: "memory");
  SCHED0;
  __builtin_amdgcn_s_barrier();
  SCHED0;
  {
    int idx = 8 * w + (lane & 7);
    float tot = spart[0][idx] + spart[1][idx] + spart[2][idx] + spart[3][idx];
    if (lane < 8) attns[(size_t)b * S_ + sblk + (CHUNKS - 1) * 32 + idx] = tot;
  }
}

// Fused tail (wsT path): softmax1 + context(from wsT) + c2 + stage2 scores
// (MFMA from wsT) + mask + final softmax. One block per batch, 512 threads.
__global__ __launch_bounds__(512) void fuse2(
    const float* __restrict__ attns, const unsigned short* __restrict__ wsT,
    const unsigned short* __restrict__ wsA, const float* __restrict__ W2,
    const float* __restrict__ v2, const unsigned char* __restrict__ mask8,
    const int* __restrict__ flag, float* __restrict__ out) {
  const int b = blockIdx.x;
  const int tid = threadIdx.x;
  const int lane = tid & 63, wv = tid >> 6, g = lane >> 4, li = lane & 15;
  __shared__ float buf[S_];
  __shared__ float sctx[8][H_];
  __shared__ float2 sq[H_];
  __shared__ float wred[8];
  __shared__ float sred;

  const size_t pbase = (size_t)b * (S_ / 16);

  // ---- Phase A: softmax(attns) ----
  float a[4];
  #pragma unroll
  for (int i = 0; i < 4; ++i) a[i] = attns[(size_t)b * S_ + i * 512 + tid];
  float mx = fmaxf(fmaxf(a[0], a[1]), fmaxf(a[2], a[3]));
  #pragma unroll
  for (int off = 32; off >= 1; off >>= 1) mx = fmaxf(mx, __shfl_xor(mx, off));
  if (lane == 0) wred[wv] = mx;
  __syncthreads();
  if (tid == 0) {
    float m = wred[0];
    #pragma unroll
    for (int i = 1; i < 8; ++i) m = fmaxf(m, wred[i]);
    sred = m;
  }
  __syncthreads();
  mx = sred;
  __syncthreads();
  float sum = 0.f;
  #pragma unroll
  for (int i = 0; i < 4; ++i) {
    float e = __expf(a[i] - mx);
    buf[i * 512 + tid] = e;
    sum += e;
  }
  #pragma unroll
  for (int off = 32; off >= 1; off >>= 1) sum += __shfl_xor(sum, off);
  if (lane == 0) wred[wv] = sum;
  __syncthreads();
  if (tid == 0) {
    float s = 0.f;
    #pragma unroll
    for (int i = 0; i < 8; ++i) s += wred[i];
    sred = 1.0f / s;
  }
  __syncthreads();
  const float inv1 = sred;
  __syncthreads();

  // ---- Phase B: ctx partials from wsT ----
  float hacc[4][8];
  #pragma unroll
  for (int t = 0; t < 4; ++t)
    #pragma unroll
    for (int j = 0; j < 8; ++j) hacc[t][j] = 0.f;
  short8 cur[4];
  #pragma unroll
  for (int t = 0; t < 4; ++t)
    cur[t] = *(const short8*)&wsT[((pbase + wv) * 4 + t) * 512 + lane * 8];
  for (int stile = wv; stile < 128; stile += 8) {
    short8 nxt[4];
    const bool more = (stile + 8) < 128;
    if (more) {
      #pragma unroll
      for (int t = 0; t < 4; ++t)
        nxt[t] = *(const short8*)&wsT[((pbase + stile + 8) * 4 + t) * 512 + lane * 8];
    }
    float pw = buf[stile * 16 + li];
    #pragma unroll
    for (int t = 0; t < 4; ++t)
      #pragma unroll
      for (int j = 0; j < 8; ++j)
        hacc[t][j] = fmaf(pw, bf2f((unsigned short)cur[t][j]), hacc[t][j]);
    if (more) {
      #pragma unroll
      for (int t = 0; t < 4; ++t) cur[t] = nxt[t];
    }
  }
  #pragma unroll
  for (int t = 0; t < 4; ++t)
    #pragma unroll
    for (int j = 0; j < 8; ++j) {
      float x = hacc[t][j];
      x += __shfl_xor(x, 1); x += __shfl_xor(x, 2);
      x += __shfl_xor(x, 4); x += __shfl_xor(x, 8);
      hacc[t][j] = x;
    }
  if (li == 0) {
    #pragma unroll
    for (int t = 0; t < 4; ++t)
      #pragma unroll
      for (int j = 0; j < 8; ++j)
        sctx[wv][32 * t + 8 * g + j] = hacc[t][j];
  }
  __syncthreads();

  // ---- Phase C: ctx reduce + c2 ----
  if (tid < 128) {
    float cx = 0.f;
    #pragma unroll
    for (int q = 0; q < 8; ++q) cx += sctx[q][tid];
    sctx[0][tid] = cx * inv1;
  }
  __syncthreads();
  if (tid < 128) {
    const float* wr = W2 + tid * 256 + 128;
    float c2v = 0.f;
    #pragma unroll 4
    for (int k = 0; k < 128; ++k) c2v += wr[k] * sctx[0][k];
    sq[tid] = make_float2(c2v, v2[tid]);
  }
  __syncthreads();

  // ---- Phase D: stage-2 scores ----
  short8 aW[8][4];
  #pragma unroll
  for (int m = 0; m < 8; ++m)
    #pragma unroll
    for (int t = 0; t < 4; ++t)
      aW[m][t] = *(const short8*)(wsA + (size_t)(((8 + m) * 4 + t) * 64 + lane) * 8);
  const int f = *flag;

  short8 bcur[4];
  #pragma unroll
  for (int t = 0; t < 4; ++t)
    bcur[t] = *(const short8*)&wsT[((pbase + wv) * 4 + t) * 512 + lane * 8];
  for (int stile = wv; stile < 128; stile += 8) {
    short8 bnxt[4];
    const bool more = (stile + 8) < 128;
    if (more) {
      #pragma unroll
      for (int t = 0; t < 4; ++t)
        bnxt[t] = *(const short8*)&wsT[((pbase + stile + 8) * 4 + t) * 512 + lane * 8];
    }
    f32x4 acc[8];
    #pragma unroll
    for (int m = 0; m < 8; ++m) acc[m] = (f32x4)0.0f;
    #pragma unroll
    for (int t = 0; t < 4; ++t)
      #pragma unroll
      for (int m = 0; m < 8; ++m)
        acc[m] = __builtin_amdgcn_mfma_f32_16x16x32_bf16(aW[m][t], bcur[t], acc[m], 0, 0, 0);
    float part = 0.f;
    #pragma unroll
    for (int m = 0; m < 8; ++m)
      #pragma unroll
      for (int r = 0; r < 4; ++r) {
        float2 q = sq[16 * m + 4 * g + r];
        part += q.y * tanh5(acc[m][r] + q.x);
      }
    part += __shfl_xor(part, 16);
    part += __shfl_xor(part, 32);
    if (lane < 16) {
      int s = stile * 16 + li;
      size_t mi = (size_t)b * S_ + s;
      bool msk;
      if (f == 1)      msk = mask8[mi] != 0;
      else if (f == 2) msk = ((const float*)mask8)[mi] != 0.0f;
      else             msk = ((const int*)mask8)[mi] != 0;
      buf[s] = msk ? -INFINITY : part;
    }
    if (more) {
      #pragma unroll
      for (int t = 0; t < 4; ++t) bcur[t] = bnxt[t];
    }
  }
  __syncthreads();

  // ---- Phase E: final softmax ----
  float s4[4];
  #pragma unroll
  for (int i = 0; i < 4; ++i) s4[i] = buf[i * 512 + tid];
  float mx2 = fmaxf(fmaxf(s4[0], s4[1]), fmaxf(s4[2], s4[3]));
  #pragma unroll
  for (int off = 32; off >= 1; off >>= 1) mx2 = fmaxf(mx2, __shfl_xor(mx2, off));
  if (lane == 0) wred[wv] = mx2;
  __syncthreads();
  if (tid == 0) {
    float m = wred[0];
    #pragma unroll
    for (int i = 1; i < 8; ++i) m = fmaxf(m, wred[i]);
    sred = m;
  }
  __syncthreads();
  mx2 = sred;
  __syncthreads();
  float e4[4];
  float sum2 = 0.f;
  #pragma unroll
  for (int i = 0; i < 4; ++i) { e4[i] = __expf(s4[i] - mx2); sum2 += e4[i]; }
  #pragma unroll
  for (int off = 32; off >= 1; off >>= 1) sum2 += __shfl_xor(sum2, off);
  if (lane == 0) wred[wv] = sum2;
  __syncthreads();
  if (tid == 0) {
    float s = 0.f;
    #pragma unroll
    for (int i = 0; i < 8; ++i) s += wred[i];
    sred = 1.0f / s;
  }
  __syncthreads();
  const float inv2 = sred;
  #pragma unroll
  for (int i = 0; i < 4; ++i) out[(size_t)b * S_ + i * 512 + tid] = e4[i] * inv2;
}

// ================= fallback path (no wsT): R5 structure =================
__global__ __launch_bounds__(256) void stage1_fb(
    const float* __restrict__ sEmb, const float* __restrict__ dEmb,
    const unsigned short* __restrict__ wsA, const float* __restrict__ c1,
    const float* __restrict__ v, float* __restrict__ attns) {
  const int b = blockIdx.y;
  const int tid = threadIdx.x;
  const int lane = tid & 63, w = tid >> 6, g = lane >> 4, li = lane & 15;
  __shared__ float sS[128 * 64];
  __shared__ unsigned short frag[4][8][512];
  __shared__ float spart[256];
  __shared__ float sc1[H_], sv[H_];

  const size_t sbase = (size_t)b * H_ * S_;
  const size_t dbase = (size_t)b * S_ * H_;
  const int sblk = blockIdx.x * 512;

  short8 aW[2][4], aB[2][4];
  #pragma unroll
  for (int mm = 0; mm < 2; ++mm)
    #pragma unroll
    for (int t = 0; t < 4; ++t) {
      aW[mm][t] = *(const short8*)(wsA + (size_t)(((2 * w + mm) * 4 + t) * 64 + lane) * 8);
      aB[mm][t] = *(const short8*)(wsA + (size_t)(((16 + 2 * w + mm) * 4 + t) * 64 + lane) * 8);
    }
  if (tid < 128) { sc1[tid] = c1[b * H_ + tid]; sv[tid] = v[tid]; }

  const int lrow = lane >> 4, lcol4 = 4 * (lane & 15);
  auto stageS = [&](int soff) {
    #pragma unroll
    for (int i = 0; i < 8; ++i) {
      int r = 32 * w + 4 * i + lrow;
      int gcol = lcol4 ^ (((r >> 3) & 3) << 3);
      const float* src = sEmb + sbase + (size_t)r * S_ + soff + gcol;
      __builtin_amdgcn_global_load_lds((gvoid_t*)src, (lvoid_t*)&sS[(32 * w + 4 * i) * 64],
                                       16, 0, 0);
    }
  };
  f32x4 dv[8];
  auto loadD = [&](int soff) {
    const float* dr = dEmb + dbase + (size_t)(soff + 16 * w + li) * H_ + 8 * g;
    #pragma unroll
    for (int t = 0; t < 4; ++t) {
      dv[2 * t]     = *(const f32x4*)(dr + 32 * t);
      dv[2 * t + 1] = *(const f32x4*)(dr + 32 * t + 4);
    }
  };
  stageS(sblk);
  loadD(sblk);
  const int colA = (16 * w + li) ^ (g << 3);

  for (int c = 0; c < 8; ++c) {
    const int soff = sblk + c * 64;
    __syncthreads();
    if (c > 0 && tid < 64)
      attns[(size_t)b * S_ + soff - 64 + tid] =
          spart[tid] + spart[64 + tid] + spart[128 + tid] + spart[192 + tid];
    #pragma unroll
    for (int t = 0; t < 4; ++t) {
      const int rb = (32 * t + 8 * g) * 64 + colA;
      uint32_t s0 = cvtpk(sS[rb], sS[rb + 64]);
      uint32_t s1 = cvtpk(sS[rb + 128], sS[rb + 192]);
      uint32_t s2 = cvtpk(sS[rb + 256], sS[rb + 320]);
      uint32_t s3 = cvtpk(sS[rb + 384], sS[rb + 448]);
      u32x4 us = {s0, s1, s2, s3};
      short8 bS = __builtin_bit_cast(short8, us);
      uint32_t d0 = cvtpk(dv[2 * t].x, dv[2 * t].y);
      uint32_t d1 = cvtpk(dv[2 * t].z, dv[2 * t].w);
      uint32_t d2 = cvtpk(dv[2 * t + 1].x, dv[2 * t + 1].y);
      uint32_t d3 = cvtpk(dv[2 * t + 1].z, dv[2 * t + 1].w);
      u32x4 ud = {d0, d1, d2, d3};
      short8 bD = __builtin_bit_cast(short8, ud);
      *(short8*)&frag[w][t][lane * 8] = bS;
      *(short8*)&frag[w][4 + t][lane * 8] = bD;
    }
    __syncthreads();
    if (c + 1 < 8) { stageS(soff + 64); loadD(soff + 64); }
    f32x4 acc[4][2];
    #pragma unroll
    for (int st = 0; st < 4; ++st) { acc[st][0] = (f32x4)0.0f; acc[st][1] = (f32x4)0.0f; }
    #pragma unroll
    for (int st = 0; st < 4; ++st)
      #pragma unroll
      for (int t = 0; t < 4; ++t) {
        short8 bS = *(const short8*)&frag[st][t][lane * 8];
        short8 bD = *(const short8*)&frag[st][4 + t][lane * 8];
        acc[st][0] = __builtin_amdgcn_mfma_f32_16x16x32_bf16(aW[0][t], bS, acc[st][0], 0, 0, 0);
        acc[st][1] = __builtin_amdgcn_mfma_f32_16x16x32_bf16(aW[1][t], bS, acc[st][1], 0, 0, 0);
        acc[st][0] = __builtin_amdgcn_mfma_f32_16x16x32_bf16(aB[0][t], bD, acc[st][0], 0, 0, 0);
        acc[st][1] = __builtin_amdgcn_mfma_f32_16x16x32_bf16(aB[1][t], bD, acc[st][1], 0, 0, 0);
      }
    #pragma unroll
    for (int st = 0; st < 4; ++st) {
      float part = 0.f;
      #pragma unroll
      for (int mm = 0; mm < 2; ++mm)
        #pragma unroll
        for (int r = 0; r < 4; ++r) {
          int h = 32 * w + 16 * mm + 4 * g + r;
          part += sv[h] * tanh5(acc[st][mm][r] + sc1[h]);
        }
      part += __shfl_xor(part, 16);
      part += __shfl_xor(part, 32);
      if (lane < 16) spart[w * 64 + st * 16 + li] = part;
    }
  }
  __syncthreads();
  if (tid < 64)
    attns[(size_t)b * S_ + sblk + 448 + tid] =
        spart[tid] + spart[64 + tid] + spart[128 + tid] + spart[192 + tid];
}

__global__ __launch_bounds__(256) void kmid_a(
    const float* __restrict__ attns, const float* __restrict__ sEmb,
    float* __restrict__ ctx) {
  int q = blockIdx.x, b = blockIdx.y;
  int tid = threadIdx.x, lane = tid & 63, w = tid >> 6;
  __shared__ float p[S_];
  __shared__ float wred[4];
  __shared__ float sred;
  float a[8];
  #pragma unroll
  for (int i = 0; i < 8; ++i) a[i] = attns[(size_t)b * S_ + i * 256 + tid];
  float mx = a[0];
  #pragma unroll
  for (int i = 1; i < 8; ++i) mx = fmaxf(mx, a[i]);
  #pragma unroll
  for (int off = 32; off >= 1; off >>= 1) mx = fmaxf(mx, __shfl_xor(mx, off));
  if (lane == 0) wred[w] = mx;
  __syncthreads();
  if (tid == 0) sred = fmaxf(fmaxf(wred[0], wred[1]), fmaxf(wred[2], wred[3]));
  __syncthreads();
  mx = sred;
  __syncthreads();
  float sum = 0.f;
  #pragma unroll
  for (int i = 0; i < 8; ++i) {
    float e = __expf(a[i] - mx);
    p[i * 256 + tid] = e;
    sum += e;
  }
  #pragma unroll
  for (int off = 32; off >= 1; off >>= 1) sum += __shfl_xor(sum, off);
  if (lane == 0) wred[w] = sum;
  __syncthreads();
  if (tid == 0) sred = 1.0f / (wred[0] + wred[1] + wred[2] + wred[3]);
  __syncthreads();
  float inv = sred;
  #pragma unroll
  for (int hh = 0; hh < 8; ++hh) {
    int h = q * 32 + w * 8 + hh;
    const f32x4* xp = (const f32x4*)(sEmb + (size_t)b * H_ * S_ + (size_t)h * S_);
    float av = 0.f;
    #pragma unroll
    for (int it = 0; it < 8; ++it) {
      f32x4 x = xp[it * 64 + lane];
      f32x4 pp = *(const f32x4*)&p[(it * 64 + lane) * 4];
      av += x.x * pp.x + x.y * pp.y + x.z * pp.z + x.w * pp.w;
    }
    #pragma unroll
    for (int off = 32; off >= 1; off >>= 1) av += __shfl_xor(av, off);
    if (lane == 0) ctx[b * H_ + h] = av * inv;
  }
}

__global__ __launch_bounds__(128) void kmid_b(
    const float* __restrict__ W2, const float* __restrict__ ctx,
    float* __restrict__ c2) {
  int b = blockIdx.x;
  int h = threadIdx.x;
  __shared__ float sc[H_];
  sc[h] = ctx[b * H_ + h];
  __syncthreads();
  const float* wr = W2 + h * 256 + 128;
  float acc = 0.f;
  #pragma unroll 4
  for (int k = 0; k < 128; ++k) acc += wr[k] * sc[k];
  c2[b * H_ + h] = acc;
}

__global__ __launch_bounds__(256) void stage2F(
    const float* __restrict__ sEmb, const unsigned short* __restrict__ wsA,
    const float* __restrict__ c2, const float* __restrict__ v2,
    const unsigned char* __restrict__ mask8, const int* __restrict__ flag,
    float* __restrict__ score) {
  int b = blockIdx.y;
  int tid = threadIdx.x;
  int lane = tid & 63, w = tid >> 6, g = lane >> 4, li = lane & 15;
  __shared__ float sS[128 * 64];
  __shared__ float sc2[H_], sv2[H_];
  __shared__ float spart[256];
  const int schunk = blockIdx.x * 64;
  const size_t sbase = (size_t)b * H_ * S_;
  short8 aW[2][4];
  #pragma unroll
  for (int mm = 0; mm < 2; ++mm)
    #pragma unroll
    for (int t = 0; t < 4; ++t)
      aW[mm][t] = *(const short8*)(wsA + (size_t)(((8 + 2 * w + mm) * 4 + t) * 64 + lane) * 8);
  {
    int lrow = lane >> 4, lcol4 = 4 * (lane & 15);
    #pragma unroll
    for (int i = 0; i < 8; ++i) {
      int r = 32 * w + 4 * i + lrow;
      int gcol = lcol4 ^ (((r >> 3) & 3) << 3);
      const float* src = sEmb + sbase + (size_t)r * S_ + schunk + gcol;
      __builtin_amdgcn_global_load_lds((gvoid_t*)src, (lvoid_t*)&sS[(32 * w + 4 * i) * 64],
                                       16, 0, 0);
    }
  }
  if (tid < 128) { sc2[tid] = c2[b * H_ + tid]; sv2[tid] = v2[tid]; }
  __syncthreads();
  f32x4 acc[4][2];
  #pragma unroll
  for (int st = 0; st < 4; ++st) { acc[st][0] = (f32x4)0.0f; acc[st][1] = (f32x4)0.0f; }
  #pragma unroll
  for (int st = 0; st < 4; ++st) {
    const int colA = (16 * st + li) ^ (g << 3);
    #pragma unroll
    for (int t = 0; t < 4; ++t) {
      short8 bS;
      #pragma unroll
      for (int j = 0; j < 8; ++j)
        bS[j] = (short)f2bf(sS[(32 * t + 8 * g + j) * 64 + colA]);
      acc[st][0] = __builtin_amdgcn_mfma_f32_16x16x32_bf16(aW[0][t], bS, acc[st][0], 0, 0, 0);
      acc[st][1] = __builtin_amdgcn_mfma_f32_16x16x32_bf16(aW[1][t], bS, acc[st][1], 0, 0, 0);
    }
  }
  #pragma unroll
  for (int st = 0; st < 4; ++st) {
    float part = 0.f;
    #pragma unroll
    for (int mm = 0; mm < 2; ++mm)
      #pragma unroll
      for (int r = 0; r < 4; ++r) {
        int h = 32 * w + 16 * mm + 4 * g + r;
        part += sv2[h] * tanh5(acc[st][mm][r] + sc2[h]);
      }
    part += __shfl_xor(part, 16);
    part += __shfl_xor(part, 32);
    if (lane < 16) spart[w * 64 + st * 16 + li] = part;
  }
  __syncthreads();
  if (tid < 64) {
    float tot = spart[tid] + spart[64 + tid] + spart[128 + tid] + spart[192 + tid];
    size_t mi = (size_t)b * S_ + schunk + tid;
    int f = *flag;
    bool msk;
    if (f == 1)      msk = mask8[mi] != 0;
    else if (f == 2) msk = ((const float*)mask8)[mi] != 0.0f;
    else             msk = ((const int*)mask8)[mi] != 0;
    score[mi] = msk ? -INFINITY : tot;
  }
}

__global__ __launch_bounds__(256) void ksoftmax(
    const float* __restrict__ score, float* __restrict__ out) {
  int b = blockIdx.x;
  int tid = threadIdx.x, lane = tid & 63, w = tid >> 6;
  __shared__ float wred[4];
  __shared__ float sred;
  float a[8];
  #pragma unroll
  for (int i = 0; i < 8; ++i) a[i] = score[(size_t)b * S_ + i * 256 + tid];
  float mx = a[0];
  #pragma unroll
  for (int i = 1; i < 8; ++i) mx = fmaxf(mx, a[i]);
  #pragma unroll
  for (int off = 32; off >= 1; off >>= 1) mx = fmaxf(mx, __shfl_xor(mx, off));
  if (lane == 0) wred[w] = mx;
  __syncthreads();
  if (tid == 0) sred = fmaxf(fmaxf(wred[0], wred[1]), fmaxf(wred[2], wred[3]));
  __syncthreads();
  mx = sred;
  __syncthreads();
  float e[8];
  float sum = 0.f;
  #pragma unroll
  for (int i = 0; i < 8; ++i) { e[i] = __expf(a[i] - mx); sum += e[i]; }
  #pragma unroll
  for (int off = 32; off >= 1; off >>= 1) sum += __shfl_xor(sum, off);
  if (lane == 0) wred[w] = sum;
  __syncthreads();
  if (tid == 0) sred = 1.0f / (wred[0] + wred[1] + wred[2] + wred[3]);
  __syncthreads();
  float inv = sred;
  #pragma unroll
  for (int i = 0; i < 8; ++i) out[(size_t)b * S_ + i * 256 + tid] = e[i] * inv;
}

extern "C" void kernel_launch(void* const* d_in, const int* in_sizes, int n_in,
                              void* d_out, int out_size, void* d_ws, size_t ws_size,
                              hipStream_t stream) {
  (void)in_sizes; (void)n_in; (void)out_size;
  if (ws_size < WS_NEED) return;
  const float* sEmb = (const float*)d_in[0];
  const float* dEmb = (const float*)d_in[1];
  const float* dec  = (const float*)d_in[2];
  const unsigned char* mask = (const unsigned char*)d_in[3];
  const float* v    = (const float*)d_in[4];
  const float* W    = (const float*)d_in[5];
  const float* v2   = (const float*)d_in[6];
  const float* W2   = (const float*)d_in[7];

  char* ws = (char*)d_ws;
  unsigned short* wsA = (unsigned short*)(ws);
  int*   flag  = (int*)  (ws + 114688);
  float* c1    = (float*)(ws + 131072);
  float* c2    = (float*)(ws + 262144);
  float* ctx   = (float*)(ws + 393216);
  float* attns = (float*)(ws + 524288);
  float* score = (float*)(ws + 2621440);
  bool useT = (ws_size >= WS_T_NEED);
  unsigned short* wsT = useT ? (unsigned short*)(ws + WST_OFF) : nullptr;

  prep_wfrags<<<192, 256, 0, stream>>>(W, W2, wsA);
  prep_c1<<<B_, 128, 0, stream>>>(W, dec, c1);
  detect_mask<<<1, 256, 0, stream>>>(mask, flag);
  if (useT) {
    stage1<<<dim3(8, B_), 256, 0, stream>>>(sEmb, dEmb, wsA, c1, v, attns, wsT);
    fuse2<<<B_, 512, 0, stream>>>(attns, wsT, wsA, W2, v2, mask, flag, (float*)d_out);
  } else {
    stage1_fb<<<dim3(4, B_), 256, 0, stream>>>(sEmb, dEmb, wsA, c1, v, attns);
    kmid_a<<<dim3(4, B_), 256, 0, stream>>>(attns, sEmb, ctx);
    kmid_b<<<B_, 128, 0, stream>>>(W2, ctx, c2);
    stage2F<<<dim3(32, B_), 256, 0, stream>>>(sEmb, wsA, c2, v2, mask, flag, score);
    ksoftmax<<<B_, 256, 0, stream>>>(score, (float*)d_out);
  }
}